// Round 11
// baseline (331.556 us; speedup 1.0000x reference)
//
#include <hip/hip_runtime.h>
#include <hip/hip_bf16.h>
#include <stdint.h>

typedef __attribute__((ext_vector_type(8))) __bf16 bf16x8;
typedef __attribute__((ext_vector_type(4))) float  f32x4;

// ---------- bf16 helpers (bf16 pairs packed in uint32, little-endian) ----------
__device__ __forceinline__ float bflo(uint32_t p){ return __uint_as_float(p << 16); }
__device__ __forceinline__ float bfhi(uint32_t p){ return __uint_as_float(p & 0xffff0000u); }
__device__ __forceinline__ uint16_t f2bf(float f){
    uint32_t u = __float_as_uint(f);
    uint32_t r = (u + 0x7fffu + ((u >> 16) & 1u)) >> 16;   // RNE
    return (uint16_t)r;
}
__device__ __forceinline__ uint32_t packbf(float a, float b){
    return (uint32_t)f2bf(a) | ((uint32_t)f2bf(b) << 16);
}
__device__ __forceinline__ f32x4 MFMA(bf16x8 a, bf16x8 b, f32x4 c){
    return __builtin_amdgcn_mfma_f32_16x16x32_bf16(a, b, c, 0, 0, 0);
}

// Mean buffer lives in the SECOND HALF of each f32 Emb row (u32 units);
// Xbf (layer-1 bf16 input) lives in the FIRST HALF.

// ---------- weight pack helper (shared by k_prep / k_bnwprep2) ----------
// Wpk u16 layout: [kt(8)][sel(2: hi,lo)][slot(512)][e(8)]
//   slot(c,g) = 4*c + (g ^ ((c>>1)&3))   (bank swizzle for conflict-free ds_read_b128)
__device__ __forceinline__ void wpack_one(uint16_t* __restrict__ Wpk, int idx, float v){
    int c = idx >> 8, k = idx & 255;
    uint16_t h = f2bf(v);
    float r = v - __uint_as_float((uint32_t)h << 16);
    int kt = k >> 5, kk = k & 31;
    int g = kk >> 3, e = kk & 7;
    int slot = (c << 2) | (g ^ ((c >> 1) & 3));
    size_t base = (size_t)kt * 8192 + (size_t)slot * 8 + e;
    Wpk[base]        = h;
    Wpk[base + 4096] = f2bf(r);
}

// ---------- fused prep: wprep1 | x2bf (grid-stride) | deg (grid-stride, 2-edge ILP) --
__global__ __launch_bounds__(256) void k_prep(
        const float* __restrict__ X, uint32_t* __restrict__ XbfE, uint32_t* __restrict__ Xlo,
        const int* __restrict__ dst, int* __restrict__ counts,
        const float* __restrict__ W1l, const float* __restrict__ W1r,
        uint16_t* __restrict__ Wpk1, float* __restrict__ bnsum,
        int N, int E){
    int bid = blockIdx.x, tid = threadIdx.x;
    if (bid < 128){
        if (bid == 0) bnsum[tid] = 0.f;              // bnsum[128]+bnsumsq[128] contiguous
        int idx = bid * 256 + tid;                   // [0, 32768) = c*256 + k
        int k = idx & 255, c = idx >> 8;
        float v = (k < 128) ? W1l[k * 128 + c] : W1r[(k - 128) * 128 + c];
        wpack_one(Wpk1, idx, v);
    } else if (bid < 128 + 1024){
        const int stride = 1024 * 256;
        for (int i = (bid - 128) * 256 + tid; i < N * 32; i += stride){
            int row = i >> 5, l = i & 31;
            float4 v = *(const float4*)(X + (size_t)i * 4);
            uint16_t h0 = f2bf(v.x), h1 = f2bf(v.y), h2 = f2bf(v.z), h3 = f2bf(v.w);
            float r0 = v.x - __uint_as_float((uint32_t)h0 << 16);
            float r1 = v.y - __uint_as_float((uint32_t)h1 << 16);
            float r2 = v.z - __uint_as_float((uint32_t)h2 << 16);
            float r3 = v.w - __uint_as_float((uint32_t)h3 << 16);
            uint2 hi; hi.x = (uint32_t)h0 | ((uint32_t)h1 << 16);
            hi.y = (uint32_t)h2 | ((uint32_t)h3 << 16);
            uint2 lo; lo.x = packbf(r0, r1); lo.y = packbf(r2, r3);
            *(uint2*)(XbfE + (size_t)row * 128 + l * 2) = hi;
            *(uint2*)(Xlo  + (size_t)row * 64  + l * 2) = lo;
        }
    } else {
        // 2 edges per thread per iteration (int2 loads; E even in practice, tail-guarded)
        const int stride = 1024 * 256 * 2;
        int e = ((bid - 1152) * 256 + tid) * 2;
        for (; e + 1 < E; e += stride){
            int2 d2 = *(const int2*)(dst + e);
            atomicAdd(&counts[d2.x], 1);
            atomicAdd(&counts[d2.y], 1);
        }
        if (e < E) atomicAdd(&counts[dst[e]], 1);
    }
}

// ---------- CSR scans ----------
__global__ void k_scan1(const int* __restrict__ counts, int* __restrict__ bsums, int N){
    __shared__ int lds[256];
    int t = threadIdx.x;
    int base = blockIdx.x * 2048 + t * 8;
    int s = 0;
    #pragma unroll
    for (int i = 0; i < 8; ++i){ int idx = base + i; s += (idx < N) ? counts[idx] : 0; }
    lds[t] = s; __syncthreads();
    for (int off = 128; off > 0; off >>= 1){
        if (t < off) lds[t] += lds[t + off];
        __syncthreads();
    }
    if (t == 0) bsums[blockIdx.x] = lds[0];
}

// scan3 computes its own prefix of bsums (one wave, NB<=64) — no k_scan2.
__global__ void k_scan3(const int* __restrict__ counts, const int* __restrict__ bsums,
                        int* __restrict__ offs, int N){
    __shared__ int lds[256];
    __shared__ int base_s;
    int t = threadIdx.x;
    if (t < 64){
        int s2 = 0;
        for (int i = t; i < (int)blockIdx.x; i += 64) s2 += bsums[i];
        #pragma unroll
        for (int m = 32; m >= 1; m >>= 1) s2 += __shfl_xor(s2, m, 64);
        if (t == 0) base_s = s2;
    }
    int base = blockIdx.x * 2048 + t * 8;
    int local[8];
    int s = 0;
    #pragma unroll
    for (int i = 0; i < 8; ++i){
        int idx = base + i;
        int v = (idx < N) ? counts[idx] : 0;
        local[i] = v; s += v;
    }
    lds[t] = s; __syncthreads();                     // also publishes base_s
    for (int off = 1; off < 256; off <<= 1){
        int v = (t >= off) ? lds[t - off] : 0;
        __syncthreads();
        lds[t] += v;
        __syncthreads();
    }
    int run = base_s + (lds[t] - s);
    #pragma unroll
    for (int i = 0; i < 8; ++i){
        int idx = base + i;
        if (idx < N){ offs[idx] = run; run += local[i]; }
    }
}

// 2-edge ILP fill: two independent atomic+scatter chains in flight per thread.
__global__ void k_fill(const int* __restrict__ src, const int* __restrict__ dst,
                       const int* __restrict__ offs, int* __restrict__ cursor,
                       int* __restrict__ ssrc, int E){
    const int stride = gridDim.x * 256 * 2;
    int e = (blockIdx.x * 256 + threadIdx.x) * 2;
    for (; e + 1 < E; e += stride){
        int2 s2 = *(const int2*)(src + e);
        int2 d2 = *(const int2*)(dst + e);
        int o0 = offs[d2.x];
        int o1 = offs[d2.y];
        int p0 = atomicAdd(&cursor[d2.x], 1);
        int p1 = atomicAdd(&cursor[d2.y], 1);
        ssrc[o0 + p0] = s2.x;
        ssrc[o1 + p1] = s2.y;
    }
    if (e < E){
        int d = dst[e];
        int p = atomicAdd(&cursor[d], 1);
        ssrc[offs[d] + p] = src[e];
    }
}

// ---------- neighbor mean: grid-stride + software-pipelined CSR meta ----------
// 2048 blocks x 4 waves = 8192 waves.  Per node: branch-free predicated fast path
// for cnt<=8 (zero-init gather vectors, unconditional accumulate — +0.0f is exact),
// tail loop for cnt>8.  Next node's counts/offs prefetched during current gather
// (removes one serial latency level from the 3-deep chain).
template<int MODE>
__global__ __launch_bounds__(256) void k_agg(
        const uint32_t* __restrict__ Src, int sstr,
        const int* __restrict__ offs, const int* __restrict__ counts,
        const int* __restrict__ ssrc,
        const float* __restrict__ bnscale, const float* __restrict__ bnshift,
        uint32_t* __restrict__ MbBase, int N){
    const int lane = threadIdx.x & 63;
    const int l15  = lane & 15;
    const int q    = lane >> 4;
    const int nwaves = gridDim.x * 4;
    const uint32_t* srcb = Src + l15 * 4;

    float sc[8], sh[8];                              // BN fold constants (node-invariant)
    if (MODE == 1){
        int c0 = l15 * 8;
        float4 s0 = *(const float4*)(bnscale + c0);
        float4 s1 = *(const float4*)(bnscale + c0 + 4);
        float4 h0 = *(const float4*)(bnshift + c0);
        float4 h1 = *(const float4*)(bnshift + c0 + 4);
        sc[0]=s0.x; sc[1]=s0.y; sc[2]=s0.z; sc[3]=s0.w;
        sc[4]=s1.x; sc[5]=s1.y; sc[6]=s1.z; sc[7]=s1.w;
        sh[0]=h0.x; sh[1]=h0.y; sh[2]=h0.z; sh[3]=h0.w;
        sh[4]=h1.x; sh[5]=h1.y; sh[6]=h1.z; sh[7]=h1.w;
    }

    int node = blockIdx.x * 4 + (threadIdx.x >> 6);
    int cnt_c = 0, off_c = 0;
    if (node < N){ cnt_c = counts[node]; off_c = offs[node]; }

    for (; node < N; node += nwaves){
        int cnt = cnt_c; if (cnt < 0) cnt = 0;
        int off = off_c;

        // prefetch next node's CSR meta (independent of this node's chain)
        int nn = node + nwaves;
        if (nn < N){ cnt_c = counts[nn]; off_c = offs[nn]; }

        // fast path: first 8 rows, predicated loads, unconditional accumulate
        int i0 = -1, i1 = -1;
        if (q < cnt)     i0 = ssrc[off + q];
        if (q + 4 < cnt) i1 = ssrc[off + q + 4];
        uint4 v0 = {0u,0u,0u,0u}, v1 = {0u,0u,0u,0u};
        if (i0 >= 0){
            int s = (i0 >= N) ? (N - 1) : i0;
            v0 = *(const uint4*)(srcb + (size_t)s * sstr);
        }
        if (i1 >= 0){
            int s = (i1 >= N) ? (N - 1) : i1;
            v1 = *(const uint4*)(srcb + (size_t)s * sstr);
        }
        float a[8];
        a[0] = bflo(v0.x) + bflo(v1.x); a[1] = bfhi(v0.x) + bfhi(v1.x);
        a[2] = bflo(v0.y) + bflo(v1.y); a[3] = bfhi(v0.y) + bfhi(v1.y);
        a[4] = bflo(v0.z) + bflo(v1.z); a[5] = bfhi(v0.z) + bfhi(v1.z);
        a[6] = bflo(v0.w) + bflo(v1.w); a[7] = bfhi(v0.w) + bfhi(v1.w);

        // tail: cnt > 8 (rare; ~15% of nodes at E/N=6)
        for (int j = 8; j < cnt; j += 8){
            int t0 = -1, t1 = -1;
            if (q + j < cnt)     t0 = ssrc[off + j + q];
            if (q + j + 4 < cnt) t1 = ssrc[off + j + q + 4];
            uint4 w0 = {0u,0u,0u,0u}, w1 = {0u,0u,0u,0u};
            if (t0 >= 0){
                int s = (t0 >= N) ? (N - 1) : t0;
                w0 = *(const uint4*)(srcb + (size_t)s * sstr);
            }
            if (t1 >= 0){
                int s = (t1 >= N) ? (N - 1) : t1;
                w1 = *(const uint4*)(srcb + (size_t)s * sstr);
            }
            a[0] += bflo(w0.x) + bflo(w1.x); a[1] += bfhi(w0.x) + bfhi(w1.x);
            a[2] += bflo(w0.y) + bflo(w1.y); a[3] += bfhi(w0.y) + bfhi(w1.y);
            a[4] += bflo(w0.z) + bflo(w1.z); a[5] += bfhi(w0.z) + bfhi(w1.z);
            a[6] += bflo(w0.w) + bflo(w1.w); a[7] += bfhi(w0.w) + bfhi(w1.w);
        }

        // reduce across the 4 row-groups (lanes l15, l15+16, l15+32, l15+48)
        #pragma unroll
        for (int i = 0; i < 8; ++i){
            a[i] += __shfl_xor(a[i], 16, 64);
            a[i] += __shfl_xor(a[i], 32, 64);
        }
        float inv = 1.0f / fmaxf((float)cnt, 1.0f);
        #pragma unroll
        for (int i = 0; i < 8; ++i) a[i] *= inv;

        if (MODE == 1){
            if (cnt > 0){                             // ref: zero-degree mean == 0
                #pragma unroll
                for (int i = 0; i < 8; ++i) a[i] = a[i] * sc[i] + sh[i];
            } else {
                #pragma unroll
                for (int i = 0; i < 8; ++i) a[i] = 0.f;
            }
        }

        if (q == 0){
            uint4 o;
            o.x = packbf(a[0], a[1]); o.y = packbf(a[2], a[3]);
            o.z = packbf(a[4], a[5]); o.w = packbf(a[6], a[7]);
            *(uint4*)(MbBase + (size_t)node * 128 + 64 + l15 * 4) = o;
        }
    }
}

// stage one quarter (32 KiB: 4 kt of one sel) of B into sB (8-wave version).
// LDS dest is wave-uniform base (+ lane*16 by HW); global src is per-lane.
__device__ __forceinline__ void stage4(const uint32_t* Wpk, uint32_t (*sB)[2048],
                                       int wid, int lane, int sel, int half){
    #pragma unroll
    for (int i = 0; i < 4; ++i){
        int ch = wid * 4 + i;                        // 32 chunks of 1 KiB
        int ktv = ch >> 3, part = ch & 7;
        __builtin_amdgcn_global_load_lds(
            Wpk + (size_t)(half * 4 + ktv) * 4096 + sel * 2048 + part * 256 + lane * 4,
            &sB[ktv][part * 256], 16, 0, 0);
    }
}

// ---------- MFMA dual-GEMM (K=256 = [mean|own]) + L2-normalize ----------
// 512 threads = 8 waves; each wave owns 16 rows (ONE m-tile), all 128 cols.
// (R7 structure: combined VGPR+AGPR ~90 < 128 -> launch_bounds(512,4) gives
// 2 blocks/CU without spills.)  B staged in FOUR 32 KiB quarters.
// A frag:  lane holds row (lane&15), k = 32*kt + 8*(lane>>4) + e  (contiguous 16B)
// B frag:  swizzled slot; gx = g ^ ((l15>>1)&3)   (conflict-free ds_read_b128)
// C/D:     col = lane&15, row = 4*(lane>>4) + reg   (m89-verified)
// MODE 0: own=Xbf (+Xlo correction on hi); out=relu(norm(.)); Hbf store + BN sums.
// MODE 1: own=Hbf (BN folded into Wpk/bias); out=norm(.); Emb f32 + preds.
template<int MODE>
__global__ __launch_bounds__(512, 4) void k_gemm(
        const uint32_t* Own,                 // MODE0: Xbf in Emb rows (stride 128); MODE1: Hbf (stride 64)
        const uint32_t* OwnLo,               // MODE0 only: Xlo (stride 64; aliases HbfOut)
        const uint32_t* Mb,                  // bf16 means at Emb rows' 2nd half
        const uint32_t* __restrict__ Wpk,    // packed+swizzled [kt][hi/lo][512 slots][8] u16
        const float* __restrict__ bias,      // [128] effective bias
        uint32_t* HbfOut,                    // MODE0 out (aliases OwnLo; alias-safe per-wave)
        float* Emb,                          // MODE1 out (aliases Mb rows; reads precede writes)
        float* __restrict__ bnsum, float* __restrict__ bnsumsq,             // MODE0
        const float* __restrict__ fcW, const float* __restrict__ fcb,       // MODE1
        float* __restrict__ preds, int N){
    __shared__ uint32_t __align__(16) sB[4][2048];   // 32 KiB; reused 4x; aliased by lsum/lsq at end
    const int lane = threadIdx.x & 63;
    const int wid  = threadIdx.x >> 6;               // 0..7
    const int l15  = lane & 15;
    const int g    = lane >> 4;
    const int gx4  = (g ^ ((l15 >> 1) & 3)) * 4;     // swizzled 16B sub-slot (u32 units)
    const int ostr = (MODE == 0) ? 128 : 64;
    const int wrow = blockIdx.x * 128 + wid * 16;    // this wave's 16-row m-tile

    stage4(Wpk, sB, wid, lane, 0, 0);                // quarter 1: hi, kt 0-3

    int ar0 = wrow + l15; if (ar0 >= N) ar0 = N - 1; // clamped dup rows: discarded

    const uint32_t* mp0 = Mb  + (size_t)ar0 * 128 + 64 + g * 4;
    const uint32_t* op0 = Own + (size_t)ar0 * ostr + g * 4;

    // hoist ALL A fragments into registers (independent loads, overlap staging)
    bf16x8 am[4], ao[4];
    #pragma unroll
    for (int kq = 0; kq < 4; ++kq){
        am[kq] = *(const bf16x8*)(mp0 + kq * 16);
        ao[kq] = *(const bf16x8*)(op0 + kq * 16);
    }
    bf16x8 xl[4];
    if (MODE == 0){
        #pragma unroll
        for (int kq = 0; kq < 4; ++kq)
            xl[kq] = *(const bf16x8*)(OwnLo + (size_t)ar0 * 64 + g * 4 + kq * 16);
    }

    f32x4 acc[8];
    const f32x4 zero = {0.f, 0.f, 0.f, 0.f};
    #pragma unroll
    for (int t = 0; t < 8; ++t) acc[t] = zero;

#define COMPUTE4(AM, ADD_XLO)                                                 \
    _Pragma("unroll")                                                         \
    for (int kk = 0; kk < 4; ++kk){                                           \
        _Pragma("unroll")                                                     \
        for (int t = 0; t < 8; ++t){                                          \
            bf16x8 bq = *(const bf16x8*)(&sB[kk][(t * 16 + l15) * 16 + gx4]); \
            acc[t] = MFMA(AM[kk], bq, acc[t]);                                \
            if (ADD_XLO) acc[t] = MFMA(xl[kk], bq, acc[t]);                   \
        }                                                                     \
    }

    __syncthreads();                                 // q1 staged + A-loads issued
    COMPUTE4(am, false);                             // hi, kt 0-3 (mean half)
    __syncthreads();
    stage4(Wpk, sB, wid, lane, 0, 1);                // quarter 2: hi, kt 4-7
    __syncthreads();
    COMPUTE4(ao, (MODE == 0));                       // hi, kt 4-7 (own half, +xlo)
    __syncthreads();
    stage4(Wpk, sB, wid, lane, 1, 0);                // quarter 3: lo, kt 0-3
    __syncthreads();
    COMPUTE4(am, false);                             // lo, kt 0-3
    __syncthreads();
    stage4(Wpk, sB, wid, lane, 1, 1);                // quarter 4: lo, kt 4-7
    __syncthreads();
    COMPUTE4(ao, false);                             // lo, kt 4-7
#undef COMPUTE4

    // ---- epilogue ----
    float bv[8];
    #pragma unroll
    for (int t = 0; t < 8; ++t) bv[t] = bias[t * 16 + l15];

    float fw[4]; float fb = 0.f;
    if (MODE == 1){
        #pragma unroll
        for (int t = 0; t < 4; ++t) fw[t] = fcW[t * 16 + l15];
        fb = fcb[0];
    }

    float pbs[8], pbq[8];
    #pragma unroll
    for (int t = 0; t < 8; ++t){ pbs[t] = 0.f; pbq[t] = 0.f; }

    #pragma unroll
    for (int j = 0; j < 4; ++j){
        int orow = wrow + 4 * g + j;
        bool valid = orow < N;
        float o[8]; float ss = 0.f;
        #pragma unroll
        for (int t = 0; t < 8; ++t){
            o[t] = acc[t][j] + bv[t];
            ss += o[t] * o[t];
        }
        ss += __shfl_xor(ss, 1, 64);
        ss += __shfl_xor(ss, 2, 64);
        ss += __shfl_xor(ss, 4, 64);
        ss += __shfl_xor(ss, 8, 64);
        float inv = 1.0f / fmaxf(sqrtf(ss), 1e-12f);
        if (MODE == 0){
            #pragma unroll
            for (int t = 0; t < 8; ++t){
                float v = fmaxf(o[t] * inv, 0.f);
                float pv = __shfl_xor(v, 1, 64);              // partner col (uniform exec)
                if (valid){
                    pbs[t] += v; pbq[t] += v * v;
                    if (!(lane & 1))
                        HbfOut[(size_t)orow * 64 + t * 8 + (l15 >> 1)] = packbf(v, pv);
                }
            }
        } else {
            float p = 0.f;
            #pragma unroll
            for (int t = 0; t < 8; ++t){
                float v = o[t] * inv;
                if (valid) Emb[(size_t)orow * 128 + t * 16 + l15] = v;
                if (t < 4) p += v * fw[t];
            }
            p += __shfl_xor(p, 1, 64);
            p += __shfl_xor(p, 2, 64);
            p += __shfl_xor(p, 4, 64);
            p += __shfl_xor(p, 8, 64);
            if (valid && l15 == 0) preds[orow] = p + fb;
        }
    }

    if (MODE == 0){
        float* lsum = (float*)&sB[0][0];             // sB dead after last compute
        float* lsq  = lsum + 128;
        #pragma unroll
        for (int t = 0; t < 8; ++t){
            pbs[t] += __shfl_xor(pbs[t], 16, 64);
            pbs[t] += __shfl_xor(pbs[t], 32, 64);
            pbq[t] += __shfl_xor(pbq[t], 16, 64);
            pbq[t] += __shfl_xor(pbq[t], 32, 64);
        }
        __syncthreads();                             // all waves done reading sB
        if (threadIdx.x < 128){ lsum[threadIdx.x] = 0.f; lsq[threadIdx.x] = 0.f; }
        __syncthreads();
        if (lane < 16){
            #pragma unroll
            for (int t = 0; t < 8; ++t){
                atomicAdd(&lsum[t * 16 + lane], pbs[t]);
                atomicAdd(&lsq [t * 16 + lane], pbq[t]);
            }
        }
        __syncthreads();
        if (threadIdx.x < 128){
            atomicAdd(&bnsum[threadIdx.x],   lsum[threadIdx.x]);
            atomicAdd(&bnsumsq[threadIdx.x], lsq[threadIdx.x]);
        }
    }
}

// ---------- fused BN finalize + layer-2 weight pack ----------
// blocks 0..127: pack W2 (scale for k>=128 computed locally from bnsum/bnsumsq).
// block 128:     bnscale/bnshift arrays (for k_agg<1>) + bias2 = b2 + shift @ W2r.
__global__ __launch_bounds__(256) void k_bnwprep2(
        const float* __restrict__ bnsum, const float* __restrict__ bnsumsq,
        const float* __restrict__ gamma, const float* __restrict__ beta,
        const float* __restrict__ W2l, const float* __restrict__ W2r,
        const float* __restrict__ b2,
        uint16_t* __restrict__ Wpk2,
        float* __restrict__ bnscale, float* __restrict__ bnshift,
        float* __restrict__ bias2, int N){
    const float invN = 1.0f / (float)N;
    int bid = blockIdx.x, t = threadIdx.x;
    if (bid < 128){
        int idx = bid * 256 + t;
        int k = idx & 255, c = idx >> 8;
        float v;
        if (k < 128){
            v = W2l[k * 128 + c];
        } else {
            int ch = k - 128;
            float mu  = bnsum[ch] * invN;
            float var = fmaxf(bnsumsq[ch] * invN - mu * mu, 0.f);
            float sc  = gamma[ch] * (1.0f / sqrtf(var + 1e-5f));
            v = W2r[ch * 128 + c] * sc;
        }
        wpack_one(Wpk2, idx, v);
    } else {
        __shared__ float sh_l[128];
        if (t < 128){
            float mu  = bnsum[t] * invN;
            float var = fmaxf(bnsumsq[t] * invN - mu * mu, 0.f);
            float istd = 1.0f / sqrtf(var + 1e-5f);
            float sc = gamma[t] * istd;
            float sf = beta[t] - mu * sc;
            bnscale[t] = sc; bnshift[t] = sf; sh_l[t] = sf;
        }
        __syncthreads();
        if (t < 128){
            float acc = b2[t];
            for (int k2 = 0; k2 < 128; ++k2) acc += sh_l[k2] * W2r[k2 * 128 + t];
            bias2[t] = acc;
        }
    }
}

__global__ void k_sent(float* __restrict__ preds, int N, float val){
    int i = blockIdx.x * 256 + threadIdx.x;
    if (i < N) preds[i] = val;
}

// ---------- launch ----------
extern "C" void kernel_launch(void* const* d_in, const int* in_sizes, int n_in,
                              void* d_out, int out_size, void* d_ws, size_t ws_size,
                              hipStream_t stream){
    const int N = in_sizes[0] / 128;
    const int E = in_sizes[1] / 2;

    const float* x    = (const float*)d_in[0];
    const int*   ei   = (const int*)d_in[1];
    const int*   src  = ei;
    const int*   dst  = ei + E;
    const float* W1l  = (const float*)d_in[2];
    const float* b1   = (const float*)d_in[3];
    const float* W1r  = (const float*)d_in[4];
    const float* gam  = (const float*)d_in[5];
    const float* bet  = (const float*)d_in[6];
    const float* W2l  = (const float*)d_in[7];
    const float* b2   = (const float*)d_in[8];
    const float* W2r  = (const float*)d_in[9];
    const float* fcW  = (const float*)d_in[10];
    const float* fcb  = (const float*)d_in[11];

    float* preds = (float*)d_out;                 // f32 [N]
    float* Emb   = preds + N;                     // f32 [N,128]
    uint32_t* EmbU = (uint32_t*)Emb;              // Xbf (1st half) + Mb (2nd half) scratch

    char* w = (char*)d_ws;
    auto carve = [&](size_t bytes){ char* p = w; w += (bytes + 255) & ~(size_t)255; return p; };
    int*   counts  = (int*)  carve((size_t)N * 8);   // counts[N] + cursor[N], one memset
    int*   cursor  = counts + N;
    int*   offs    = (int*)  carve((size_t)N * 4);
    int*   bsums   = (int*)  carve(256 * 4);
    float* bnsum   = (float*)carve(128 * 4);      // contiguous with bnsumsq (zeroed in k_prep)
    float* bnsumsq = (float*)carve(128 * 4);
    float* bnscale = (float*)carve(128 * 4);
    float* bnshift = (float*)carve(128 * 4);
    float* bias2   = (float*)carve(128 * 4);
    int*   ssrc    = (int*)  carve((size_t)E * 4);
    uint32_t* HbfXlo = (uint32_t*)carve((size_t)N * 256);  // Xlo then Hbf (overlay, alias-safe)
    uint16_t* Wpk1 = (uint16_t*)carve(131072);    // packed+swizzled [kt][hi/lo][512][8]
    uint16_t* Wpk2 = (uint16_t*)carve(131072);
    size_t need = (size_t)(w - (char*)d_ws);
    if (ws_size < need){
        float val = 1024.f + 4.f * (float)((ws_size >> 20) > 255 ? 255 : (ws_size >> 20));
        k_sent<<<(N + 255) / 256, 256, 0, stream>>>(preds, N, val);
        return;
    }

    hipMemsetAsync(counts, 0, (size_t)N * 8, stream);

    const int NB = (N + 2047) / 2048;
    const int gb = (N + 127) / 128;

    // fused prep: wprep1 | x2bf | deg (grid-stride sections, fixed 2176 blocks)
    k_prep <<<2176, 256, 0, stream>>>(x, EmbU, HbfXlo, dst, counts,
                                      W1l, W1r, Wpk1, bnsum, N, E);
    k_scan1<<<NB, 256, 0, stream>>>(counts, bsums, N);
    k_scan3<<<NB, 256, 0, stream>>>(counts, bsums, offs, N);
    k_fill <<<2048, 256, 0, stream>>>(src, dst, offs, cursor, ssrc, E);

    // layer 1
    k_agg<0> <<<2048, 256, 0, stream>>>(EmbU, 128, offs, counts, ssrc,
                                        nullptr, nullptr, EmbU, N);
    k_gemm<0><<<gb, 512, 0, stream>>>(EmbU, HbfXlo, EmbU, (const uint32_t*)Wpk1, b1,
                                      HbfXlo, nullptr, bnsum, bnsumsq,
                                      nullptr, nullptr, nullptr, N);
    // fused BN finalize + layer-2 pack
    k_bnwprep2<<<129, 256, 0, stream>>>(bnsum, bnsumsq, gam, bet, W2l, W2r, b2,
                                        Wpk2, bnscale, bnshift, bias2, N);

    // layer 2
    k_agg<1> <<<2048, 256, 0, stream>>>(HbfXlo, 64, offs, counts, ssrc,
                                        bnscale, bnshift, EmbU, N);
    k_gemm<1><<<gb, 512, 0, stream>>>(HbfXlo, nullptr, EmbU, (const uint32_t*)Wpk2, bias2,
                                      nullptr, Emb, nullptr, nullptr,
                                      fcW, fcb, preds, N);
}